// Round 14
// baseline (154.064 us; speedup 1.0000x reference)
//
#include <hip/hip_runtime.h>

#define HW 4096
#define CCH 256
#define MOFF 432
#define PTOT 32768
#define PDIM 68
#define PIMG (PDIM*PDIM)      // 4624 padded cells per group-plane (2-wide zero border)

typedef unsigned short u16;
typedef __attribute__((ext_vector_type(8))) short short8;
typedef __attribute__((ext_vector_type(8))) unsigned short u16x8;
typedef __attribute__((ext_vector_type(4))) unsigned short u16x4;
typedef __attribute__((ext_vector_type(4))) float f32x4;

__device__ __forceinline__ u16 f2b(float f){
  unsigned int u = __float_as_uint(f);
  unsigned int rounding = 0x7FFFu + ((u >> 16) & 1u);
  return (u16)((u + rounding) >> 16);
}
__device__ __forceinline__ float b2f(u16 s){
  return __uint_as_float(((unsigned int)s) << 16);
}

// ---------------------------------------------------------------------------
// k_prepw: weight prep only. grid 1553 (unchanged).
// ---------------------------------------------------------------------------
__global__ __launch_bounds__(256) void k_prepw(
    const float* __restrict__ w1, const float* __restrict__ w2,
    const float* __restrict__ woff, const float* __restrict__ b1,
    const float* __restrict__ boff,
    const float* __restrict__ gamma, const float* __restrict__ beta,
    const float* __restrict__ mean, const float* __restrict__ var,
    u16* __restrict__ wb_big, u16* __restrict__ wb2,
    float* __restrict__ bnA, float* __restrict__ bnB,
    float* __restrict__ bcomb, u16* __restrict__ h1p){
  __shared__ float sbuf[512];
  int r = blockIdx.x, t = threadIdx.x;
  if (r < 256) wb_big[r*256 + t] = f2b(w1[r*256 + t]);
  else if (r < 336){ wb_big[(688 + (r - 256)) * 256 + t] = 0; }
  else if (r < 592){ int o = r - 336; wb2[o*256 + t] = f2b(w2[o*256 + t]); }
  else if (r == 592){
    if (t < 256){
      float sc = gamma[t] * rsqrtf(var[t] + 1e-5f);
      bnA[t] = sc;
      bnB[t] = beta[t] - mean[t] * sc;
    }
  } else if (r < 1121){
    int n = (r - 593) * 128 + (t >> 1);   // border cell index
    int seg = t & 1;
    int plane = n / 528, m = n % 528;
    int row, col;
    if (m < 136){ row = m / 68; col = m % 68; }
    else if (m < 272){ int mm = m - 136; row = 66 + mm / 68; col = mm % 68; }
    else { int mm = m - 272; row = 2 + (mm >> 2); int c4 = mm & 3; col = (c4 & 1) + 66 * (c4 >> 1); }
    u16x8 z = {};
    *reinterpret_cast<u16x8*>(&h1p[((size_t)plane * PIMG + row * PDIM + col) * 16 + seg * 8]) = z;
  } else {
    float* wr_ = sbuf;
    float* pb  = sbuf + 256;
    const int j = r - 1121;
    wr_[t] = woff[j * 256 + t];
    __syncthreads();
    float s = 0.f;
    #pragma unroll 8
    for (int m = 0; m < 256; ++m) s += wr_[m] * w1[m * 256 + t];
    wb_big[(256 + j) * 256 + t] = f2b(s);
    pb[t] = wr_[t] * b1[t];
    __syncthreads();
    if (t == 0){
      float bs = boff[j];
      for (int m = 0; m < 256; ++m) bs += pb[m];
      bcomb[j] = bs;
    }
  }
}

// ---------------------------------------------------------------------------
// k_mega v4: [h1 | om] = x * wb_big^T. Register-resident A, barrier-free
// main loop, B streamed from L2 per-lane (shared via L1 within block).
// Grid 512: block = 64 px, 4 waves x 16 px. Phase 0 (only block barriers):
// 4 LDS-transpose rounds -> each wave's A (16px x 256k) in 8 short8 frags.
// Main: 11 chunks of 64 o; per chunk/wave 32 B-frag loads + 32 MFMA into 4
// independent accs, epilogue via PER-WAVE LDS region (wave-local only).
// ---------------------------------------------------------------------------
__global__ __launch_bounds__(256, 2) void k_mega(const float* __restrict__ x,
    const u16* __restrict__ Bw, const float* __restrict__ b1,
    const float* __restrict__ bcomb, u16* __restrict__ h1p,
    u16* __restrict__ om){
  __shared__ __align__(16) u16 T_lds[64 * 72];     // 9216 B transpose staging
  __shared__ __align__(16) u16 C_lds[4][16 * 72];  // 9216 B, per-wave epilogue

  const int t = threadIdx.x;
  const int tm = blockIdx.x * 64;
  const int b = tm >> 12, ploc = tm & 4095;
  const int lane = t & 63;
  const int w = t >> 6;
  const int lr = lane & 15, ls = lane >> 4;

  // ---- Phase 0: A into registers via LDS transpose (4 rounds of 64 ch) ----
  short8 A[8];
  const float* xs = x + (size_t)b * 256 * HW + ploc;
  #pragma unroll
  for (int rnd = 0; rnd < 4; ++rnd){
    const int kc64 = rnd * 64;
    #pragma unroll
    for (int i = 0; i < 4; ++i){
      int flat = t + i * 256;
      int c_l = flat >> 4, seg = flat & 15;
      float4 v = *reinterpret_cast<const float4*>(&xs[(size_t)(kc64 + c_l) * HW + seg * 4]);
      T_lds[(seg * 4 + 0) * 72 + c_l] = f2b(v.x);
      T_lds[(seg * 4 + 1) * 72 + c_l] = f2b(v.y);
      T_lds[(seg * 4 + 2) * 72 + c_l] = f2b(v.z);
      T_lds[(seg * 4 + 3) * 72 + c_l] = f2b(v.w);
    }
    __syncthreads();
    #pragma unroll
    for (int kk = 0; kk < 2; ++kk)
      A[rnd * 2 + kk] = *reinterpret_cast<const short8*>(
        &T_lds[(w * 16 + lr) * 72 + kk * 32 + ls * 8]);
    __syncthreads();
  }

  // ---- Main loop: 11 chunks of 64 o, NO block barriers ----
  const u16* bp = Bw + (size_t)lr * 256 + ls * 8;
  u16* Cw = &C_lds[w][0];
  const int pxw = tm + w * 16;

  for (int oc = 0; oc < 11; ++oc){
    const int o0 = oc * 64;
    const u16* bpo = bp + (size_t)o0 * 256;
    f32x4 acc[4] = {};
    #pragma unroll
    for (int kf = 0; kf < 8; ++kf){
      #pragma unroll
      for (int nf = 0; nf < 4; ++nf){
        short8 bf = *reinterpret_cast<const short8*>(bpo + nf * 4096 + kf * 32);
        acc[nf] = __builtin_amdgcn_mfma_f32_16x16x32_bf16(A[kf], bf, acc[nf], 0, 0, 0);
      }
    }
    __builtin_amdgcn_wave_barrier();
    #pragma unroll
    for (int nf = 0; nf < 4; ++nf){
      int o = o0 + nf * 16 + lr;
      float bi = (o < 256) ? b1[o] : ((o < 688) ? bcomb[o - 256] : 0.f);
      #pragma unroll
      for (int j = 0; j < 4; ++j)
        Cw[(ls * 4 + j) * 72 + nf * 16 + lr] = f2b(acc[nf][j] + bi);
    }
    __builtin_amdgcn_wave_barrier();
    #pragma unroll
    for (int s = 0; s < 2; ++s){
      int flat = lane + s * 64;
      int row = flat >> 3, seg = flat & 7;
      u16x8 v = *reinterpret_cast<const u16x8*>(&Cw[row * 72 + seg * 8]);
      int px = pxw + row;
      int o = o0 + seg * 8;
      if (o < 256){
        int ii = (px >> 6) & 63, jj = px & 63;
        size_t dst = ((size_t)(b * 16 + (o >> 4)) * PIMG + (ii + 2) * PDIM + jj + 2) * 16 + (o & 15);
        *reinterpret_cast<u16x8*>(&h1p[dst]) = v;
      } else if (o < 688){
        *reinterpret_cast<u16x8*>(&om[(size_t)px * MOFF + (o - 256)]) = v;
      }
    }
    __builtin_amdgcn_wave_barrier();
  }
}

// ---------------------------------------------------------------------------
// k_sample: 4 px/block, 4-lane units, tap-record precompute, image->XCD
// swizzle (per-image 2.4 MB h1p resident in its XCD's 4 MB L2). Unchanged.
// ---------------------------------------------------------------------------
__global__ __launch_bounds__(256, 4) void k_sample(const u16* __restrict__ h1p,
    const u16* __restrict__ om, u16* __restrict__ ydcn){
  __shared__ float oms[4 * MOFF];        // 6912 B
  __shared__ float recs[5 * 576];        // 11520 B SoA: c00|c01|c10|c11|addr
  const int t = threadIdx.x;
  const int bid = blockIdx.x;
  const int img = bid & 7;
  const int loc = bid >> 3;              // 0..1023
  const int pblk = img * 4096 + loc * 4;
  if (t < 216){
    u16x8 v = *reinterpret_cast<const u16x8*>(&om[(size_t)pblk * MOFF + t * 8]);
    float4 lo, hi;
    lo.x = b2f(v[0]); lo.y = b2f(v[1]); lo.z = b2f(v[2]); lo.w = b2f(v[3]);
    hi.x = b2f(v[4]); hi.y = b2f(v[5]); hi.z = b2f(v[6]); hi.w = b2f(v[7]);
    *reinterpret_cast<float4*>(&oms[t * 8]) = lo;
    *reinterpret_cast<float4*>(&oms[t * 8 + 4]) = hi;
  }
  __syncthreads();

  #pragma unroll
  for (int i = 0; i < 3; ++i){
    int r = t + i * 256;
    if (i < 2 || r < 576){
      int px = r / 144, rm = r % 144;
      int g = rm / 9, k = rm % 9;
      const float* ob = &oms[px * MOFF + g * 27];
      float oh = ob[2 * k], ow = ob[2 * k + 1], m = ob[18 + k];
      int hw = (pblk + px) & 4095;
      float ph = (float)((hw >> 6) + k / 3 - 1) + oh;
      float pw = (float)((hw & 63) + k % 3 - 1) + ow;
      float h0f = floorf(ph), w0f = floorf(pw);
      float ah = ph - h0f, aw = pw - w0f;
      int h0 = (int)h0f, w0 = (int)w0f;
      int hc = min(max(h0, -2), 64) + 2;
      int wc = min(max(w0, -2), 64) + 2;
      float mh1 = m * ah, mh0 = m - mh1;
      float c01 = mh0 * aw, c00 = mh0 - c01;
      float c11 = mh1 * aw, c10 = mh1 - c11;
      recs[r]            = c00;
      recs[576 + r]      = c01;
      recs[1152 + r]     = c10;
      recs[1728 + r]     = c11;
      recs[2304 + r]     = __uint_as_float((unsigned)((hc * PDIM + wc) << 5));
    }
  }
  __syncthreads();

  const int px = t >> 6;
  const int g = (t >> 2) & 15;
  const int q = t & 3;
  const int p = pblk + px;
  const int xsel = q >> 1;
  const u16* lanebase = h1p + (size_t)(img * 16 + g) * PIMG * 16 + q * 8;
  const int ri = px * 144 + g * 9;
  const float* ctp = &recs[xsel * 576 + ri];
  const float* cbp = &recs[1152 + xsel * 576 + ri];
  const float* adp = &recs[2304 + ri];

  float acc[8] = {};
  #pragma unroll
  for (int k = 0; k < 9; ++k){
    float ct = ctp[k];
    float cb = cbp[k];
    unsigned off = __float_as_uint(adp[k]);
    const u16* c0 = (const u16*)((const char*)lanebase + off);
    u16x8 tv = *reinterpret_cast<const u16x8*>(c0);
    u16x8 bv = *reinterpret_cast<const u16x8*>(c0 + PDIM * 16);
    #pragma unroll
    for (int j = 0; j < 8; ++j)
      acc[j] += ct * b2f(tv[j]) + cb * b2f(bv[j]);
  }
  #pragma unroll
  for (int j = 0; j < 8; ++j)
    acc[j] += __shfl_xor(acc[j], 2, 64);
  if (q < 2){
    u16x8 o8;
    #pragma unroll
    for (int j = 0; j < 8; ++j) o8[j] = f2b(acc[j]);
    *reinterpret_cast<u16x8*>(&ydcn[(size_t)p * 256 + g * 16 + q * 8]) = o8;
  }
}

// ---------------------------------------------------------------------------
// k_gemm2: conv2 + BN + SiLU, tile 128x128, out fp32 NCHW (write-bound).
// ---------------------------------------------------------------------------
__global__ __launch_bounds__(256) void k_gemm2(const u16* __restrict__ A,
    const u16* __restrict__ Bw, const float* __restrict__ bnA,
    const float* __restrict__ bnB, float* __restrict__ out){
  __shared__ __align__(16) u16 smem[(128 + 128) * 40];
  const int t = threadIdx.x;
  const int tm = blockIdx.x * 128;
  const int tn = blockIdx.y * 128;
  const int lane = t & 63;
  const int wid = t >> 6;
  const int wr = wid >> 1, wc = wid & 1;
  constexpr int BOFF = 128 * 40;

  f32x4 acc[4][4] = {};

  for (int kc = 0; kc < 256; kc += 32){
    #pragma unroll
    for (int i = 0; i < 2; ++i){
      int v = t + i * 256;
      int row = v >> 2, cq = v & 3;
      *reinterpret_cast<u16x8*>(&smem[row * 40 + cq * 8]) =
        *reinterpret_cast<const u16x8*>(&A[(size_t)(tm + row) * 256 + kc + cq * 8]);
    }
    #pragma unroll
    for (int i = 0; i < 2; ++i){
      int v = t + i * 256;
      int row = v >> 2, cq = v & 3;
      *reinterpret_cast<u16x8*>(&smem[BOFF + row * 40 + cq * 8]) =
        *reinterpret_cast<const u16x8*>(&Bw[(size_t)(tn + row) * 256 + kc + cq * 8]);
    }
    __syncthreads();
    short8 af[4], bf[4];
    #pragma unroll
    for (int m = 0; m < 4; ++m)
      af[m] = *reinterpret_cast<const short8*>(
        &smem[(wr * 64 + m * 16 + (lane & 15)) * 40 + (lane >> 4) * 8]);
    #pragma unroll
    for (int n = 0; n < 4; ++n)
      bf[n] = *reinterpret_cast<const short8*>(
        &smem[BOFF + (wc * 64 + n * 16 + (lane & 15)) * 40 + (lane >> 4) * 8]);
    #pragma unroll
    for (int m = 0; m < 4; ++m)
      #pragma unroll
      for (int n = 0; n < 4; ++n)
        acc[m][n] = __builtin_amdgcn_mfma_f32_16x16x32_bf16(af[m], bf[n], acc[m][n], 0, 0, 0);
    __syncthreads();
  }

  const int bimg = tm >> 12;
  const int ploc = tm & 4095;
  #pragma unroll
  for (int n = 0; n < 4; ++n){
    int o = tn + wc * 64 + n * 16 + (lane & 15);
    float sA = bnA[o], sB = bnB[o];
    #pragma unroll
    for (int m = 0; m < 4; ++m){
      int prow = wr * 64 + m * 16 + ((lane >> 4) << 2);
      f32x4 st;
      #pragma unroll
      for (int j = 0; j < 4; ++j){
        float y = acc[m][n][j] * sA + sB;
        st[j] = y / (1.f + expf(-y));
      }
      *reinterpret_cast<f32x4*>(&out[((size_t)(bimg * 256 + o)) * HW + ploc + prow]) = st;
    }
  }
}

extern "C" void kernel_launch(void* const* d_in, const int* in_sizes, int n_in,
                              void* d_out, int out_size, void* d_ws, size_t ws_size,
                              hipStream_t stream) {
  const float* x     = (const float*)d_in[0];
  const float* w1    = (const float*)d_in[1];
  const float* b1    = (const float*)d_in[2];
  const float* woff  = (const float*)d_in[3];
  const float* boff  = (const float*)d_in[4];
  const float* w2    = (const float*)d_in[5];
  const float* gamma = (const float*)d_in[6];
  const float* beta  = (const float*)d_in[7];
  const float* mean  = (const float*)d_in[8];
  const float* var   = (const float*)d_in[9];
  float* out = (float*)d_out;
  (void)in_sizes; (void)n_in; (void)out_size; (void)ws_size;

  u16* h1p    = (u16*)d_ws;                               // 128 planes * 4624 * 32B = 18.9 MB
  u16* om     = h1p + (size_t)128 * PIMG * 16;            // 32768*432 = 28.3 MB
  u16* ydcn   = om + (size_t)PTOT * MOFF;                 // 32768*256 = 16.8 MB
  u16* wb_big = ydcn + (size_t)PTOT * CCH;                // 768*256 bf16
  u16* wb2    = wb_big + 768 * 256;                       // 256*256
  float* bnA  = (float*)(wb2 + 256 * 256);
  float* bnB  = bnA + 256;
  float* bcomb = bnB + 256;                               // 432 f32

  dim3 blk(256);
  k_prepw<<<dim3(1553), blk, 0, stream>>>(w1, w2, woff, b1, boff,
                                          gamma, beta, mean, var,
                                          wb_big, wb2, bnA, bnB, bcomb, h1p);
  k_mega<<<dim3(512), blk, 0, stream>>>(x, wb_big, b1, bcomb, h1p, om);
  k_sample<<<dim3(PTOT / 4), blk, 0, stream>>>(h1p, om, ydcn);
  k_gemm2<<<dim3(PTOT / 128, 2), blk, 0, stream>>>(ydcn, wb2, bnA, bnB, out);
}

// Round 15
// 101.225 us; speedup vs baseline: 1.5220x; 1.5220x over previous
//
#include <hip/hip_runtime.h>

#define HW 4096
#define CCH 256
#define MOFF 432
#define PTOT 32768
#define PDIM 68
#define PIMG (PDIM*PDIM)      // 4624 padded cells per group-plane (2-wide zero border)

typedef unsigned short u16;
typedef __attribute__((ext_vector_type(8))) short short8;
typedef __attribute__((ext_vector_type(8))) unsigned short u16x8;
typedef __attribute__((ext_vector_type(4))) unsigned short u16x4;
typedef __attribute__((ext_vector_type(4))) float f32x4;

__device__ __forceinline__ u16 f2b(float f){
  unsigned int u = __float_as_uint(f);
  unsigned int rounding = 0x7FFFu + ((u >> 16) & 1u);
  return (u16)((u + rounding) >> 16);
}
__device__ __forceinline__ float b2f(u16 s){
  return __uint_as_float(((unsigned int)s) << 16);
}

// ---------------------------------------------------------------------------
// k_prep (R8, proven): ALL independent prep in ONE launch:
//  [0,2048)     x fp32 NCHW -> xT bf16 [p][c] (64x64 LDS transpose tile)
//  [2048,2304)  wb_big rows 0..255 = bf16(w1)
//  [2304,2384)  wb_big rows 688..767 = 0 (N-pad)
//  [2384,2640)  wb2 = bf16(w2)
//  2640         BN fold
//  [2641,3169)  h1p planar border zero (528 blocks)
//  [3169,3601)  wcomb: wb_big row 256+j = bf16(woff[j] . w1); bcomb[j]
// ---------------------------------------------------------------------------
__global__ __launch_bounds__(256) void k_prep(const float* __restrict__ x,
    const float* __restrict__ w1, const float* __restrict__ w2,
    const float* __restrict__ woff, const float* __restrict__ b1,
    const float* __restrict__ boff,
    const float* __restrict__ gamma, const float* __restrict__ beta,
    const float* __restrict__ mean, const float* __restrict__ var,
    u16* __restrict__ xT, u16* __restrict__ wb_big, u16* __restrict__ wb2,
    float* __restrict__ bnA, float* __restrict__ bnB,
    float* __restrict__ bcomb, u16* __restrict__ h1p){
  __shared__ float tile[64][65];
  const int r = blockIdx.x, t = threadIdx.x;
  if (r < 2048){
    const int pb = (r & 63) * 64, cb = ((r >> 6) & 3) * 64, b = r >> 8;
    const float* src = x + ((size_t)(b * CCH + cb)) * HW + pb;
    #pragma unroll
    for (int pass = 0; pass < 4; ++pass){
      int c_l = pass * 16 + (t >> 4);
      int pq = (t & 15) * 4;
      float4 v = *reinterpret_cast<const float4*>(&src[(size_t)c_l * HW + pq]);
      tile[pq + 0][c_l] = v.x; tile[pq + 1][c_l] = v.y;
      tile[pq + 2][c_l] = v.z; tile[pq + 3][c_l] = v.w;
    }
    __syncthreads();
    #pragma unroll
    for (int pass = 0; pass < 4; ++pass){
      int p_l = pass * 16 + (t >> 4);
      int cq = (t & 15) * 4;
      u16x4 o4;
      #pragma unroll
      for (int j = 0; j < 4; ++j) o4[j] = f2b(tile[p_l][cq + j]);
      *reinterpret_cast<u16x4*>(&xT[((size_t)b * HW + pb + p_l) * CCH + cb + cq]) = o4;
    }
  }
  else if (r < 2304){ int o = r - 2048; wb_big[o*256 + t] = f2b(w1[o*256 + t]); }
  else if (r < 2384){ wb_big[(688 + (r - 2304)) * 256 + t] = 0; }
  else if (r < 2640){ int o = r - 2384; wb2[o*256 + t] = f2b(w2[o*256 + t]); }
  else if (r == 2640){
    if (t < 256){
      float sc = gamma[t] * rsqrtf(var[t] + 1e-5f);
      bnA[t] = sc;
      bnB[t] = beta[t] - mean[t] * sc;
    }
  } else if (r < 3169){
    int n = (r - 2641) * 128 + (t >> 1);   // border cell index
    int seg = t & 1;
    int plane = n / 528, m = n % 528;
    int row, col;
    if (m < 136){ row = m / 68; col = m % 68; }
    else if (m < 272){ int mm = m - 136; row = 66 + mm / 68; col = mm % 68; }
    else { int mm = m - 272; row = 2 + (mm >> 2); int c4 = mm & 3; col = (c4 & 1) + 66 * (c4 >> 1); }
    u16x8 z = {};
    *reinterpret_cast<u16x8*>(&h1p[((size_t)plane * PIMG + row * PDIM + col) * 16 + seg * 8]) = z;
  } else {
    float* wr_ = &tile[0][0];
    float* pb  = wr_ + 256;
    const int j = r - 3169;
    wr_[t] = woff[j * 256 + t];
    __syncthreads();
    float s = 0.f;
    #pragma unroll 8
    for (int m = 0; m < 256; ++m) s += wr_[m] * w1[m * 256 + t];
    wb_big[(256 + j) * 256 + t] = f2b(s);
    pb[t] = wr_[t] * b1[t];
    __syncthreads();
    if (t == 0){
      float bs = boff[j];
      for (int m = 0; m < 256; ++m) bs += pb[m];
      bcomb[j] = bs;
    }
  }
}

// ---------------------------------------------------------------------------
// k_gemm_big (R8, proven): [h1 | om] = xT * wb_big^T. Tile 256x128, BK=64.
// 4 waves 2x2 (wave tile 128x64, MF=8 NF=4). 64 MFMA per barrier pair, only
// 4 staged rounds per block. 1D grid 768 with XCD swizzle.
// cols 0-255 -> h1p planar (+b1); cols 256-687 -> om (+bcomb), guard 432.
// ---------------------------------------------------------------------------
__global__ __launch_bounds__(256, 2) void k_gemm_big(const u16* __restrict__ A,
    const u16* __restrict__ Bw, const float* __restrict__ b1,
    const float* __restrict__ bcomb, u16* __restrict__ h1p,
    u16* __restrict__ om){
  __shared__ __align__(16) u16 smem[34816];   // 69632 B: max(As+Bs staging, C_l)
  u16* As = smem;                   // 256*72
  u16* Bs = smem + 256 * 72;        // 128*72

  const int bid = blockIdx.x;
  const int xcd = bid & 7, s = bid >> 3;
  const int row_local = s / 6, cblk = s % 6;
  const int tm = (row_local * 8 + xcd) * 256;
  const int tn = cblk * 128;

  const int t = threadIdx.x;
  const int lane = t & 63;
  const int wid = t >> 6;
  const int wr = wid >> 1, wc = wid & 1;

  f32x4 acc[8][4] = {};

  for (int kc = 0; kc < 256; kc += 64){
    #pragma unroll
    for (int i = 0; i < 8; ++i){
      int idx = t + i * 256;
      int row = idx >> 3, cq = idx & 7;
      *reinterpret_cast<u16x8*>(&As[row * 72 + cq * 8]) =
        *reinterpret_cast<const u16x8*>(&A[(size_t)(tm + row) * 256 + kc + cq * 8]);
    }
    #pragma unroll
    for (int i = 0; i < 4; ++i){
      int idx = t + i * 256;
      int row = idx >> 3, cq = idx & 7;
      *reinterpret_cast<u16x8*>(&Bs[row * 72 + cq * 8]) =
        *reinterpret_cast<const u16x8*>(&Bw[(size_t)(tn + row) * 256 + kc + cq * 8]);
    }
    __syncthreads();
    #pragma unroll
    for (int kk = 0; kk < 2; ++kk){
      short8 af[8], bf[4];
      #pragma unroll
      for (int m = 0; m < 8; ++m)
        af[m] = *reinterpret_cast<const short8*>(
          &As[(wr * 128 + m * 16 + (lane & 15)) * 72 + kk * 32 + (lane >> 4) * 8]);
      #pragma unroll
      for (int n = 0; n < 4; ++n)
        bf[n] = *reinterpret_cast<const short8*>(
          &Bs[(wc * 64 + n * 16 + (lane & 15)) * 72 + kk * 32 + (lane >> 4) * 8]);
      #pragma unroll
      for (int m = 0; m < 8; ++m)
        #pragma unroll
        for (int n = 0; n < 4; ++n)
          acc[m][n] = __builtin_amdgcn_mfma_f32_16x16x32_bf16(af[m], bf[n], acc[m][n], 0, 0, 0);
    }
    __syncthreads();
  }

  constexpr int CP = 136;
  u16* C_l = smem;
  #pragma unroll
  for (int n = 0; n < 4; ++n){
    int col = wc * 64 + n * 16 + (lane & 15);
    int o = tn + col;
    float bi = (o < 256) ? b1[o] : ((o - 256 < MOFF) ? bcomb[o - 256] : 0.f);
    #pragma unroll
    for (int m = 0; m < 8; ++m){
      int r0 = wr * 128 + m * 16 + ((lane >> 4) << 2);
      #pragma unroll
      for (int j = 0; j < 4; ++j)
        C_l[(r0 + j) * CP + col] = f2b(acc[m][n][j] + bi);
    }
  }
  __syncthreads();
  #pragma unroll
  for (int pass = 0; pass < 16; ++pass){
    int row = pass * 16 + (t >> 4);
    int sg = t & 15;
    int oc = tn + sg * 8;
    int p = tm + row;
    if (tn < 256){
      int bb = p >> 12, ii = (p >> 6) & 63, jj = p & 63;
      size_t dst = ((size_t)(bb * 16 + (oc >> 4)) * PIMG + (ii + 2) * PDIM + jj + 2) * 16 + (oc & 15);
      *reinterpret_cast<u16x8*>(&h1p[dst]) =
        *reinterpret_cast<const u16x8*>(&C_l[row * CP + sg * 8]);
    } else {
      int occ = oc - 256;
      if (occ + 8 <= MOFF)
        *reinterpret_cast<u16x8*>(&om[(size_t)p * MOFF + occ]) =
          *reinterpret_cast<const u16x8*>(&C_l[row * CP + sg * 8]);
    }
  }
}

// ---------------------------------------------------------------------------
// k_sample (R13, proven): 4 px/block, 4-lane units, tap-record precompute,
// image->XCD swizzle (per-image 2.4 MB h1p resident in its XCD's 4 MB L2).
// ---------------------------------------------------------------------------
__global__ __launch_bounds__(256, 4) void k_sample(const u16* __restrict__ h1p,
    const u16* __restrict__ om, u16* __restrict__ ydcn){
  __shared__ float oms[4 * MOFF];        // 6912 B
  __shared__ float recs[5 * 576];        // 11520 B SoA: c00|c01|c10|c11|addr
  const int t = threadIdx.x;
  const int bid = blockIdx.x;
  const int img = bid & 7;
  const int loc = bid >> 3;              // 0..1023
  const int pblk = img * 4096 + loc * 4;
  if (t < 216){
    u16x8 v = *reinterpret_cast<const u16x8*>(&om[(size_t)pblk * MOFF + t * 8]);
    float4 lo, hi;
    lo.x = b2f(v[0]); lo.y = b2f(v[1]); lo.z = b2f(v[2]); lo.w = b2f(v[3]);
    hi.x = b2f(v[4]); hi.y = b2f(v[5]); hi.z = b2f(v[6]); hi.w = b2f(v[7]);
    *reinterpret_cast<float4*>(&oms[t * 8]) = lo;
    *reinterpret_cast<float4*>(&oms[t * 8 + 4]) = hi;
  }
  __syncthreads();

  #pragma unroll
  for (int i = 0; i < 3; ++i){
    int r = t + i * 256;
    if (i < 2 || r < 576){
      int px = r / 144, rm = r % 144;
      int g = rm / 9, k = rm % 9;
      const float* ob = &oms[px * MOFF + g * 27];
      float oh = ob[2 * k], ow = ob[2 * k + 1], m = ob[18 + k];
      int hw = (pblk + px) & 4095;
      float ph = (float)((hw >> 6) + k / 3 - 1) + oh;
      float pw = (float)((hw & 63) + k % 3 - 1) + ow;
      float h0f = floorf(ph), w0f = floorf(pw);
      float ah = ph - h0f, aw = pw - w0f;
      int h0 = (int)h0f, w0 = (int)w0f;
      int hc = min(max(h0, -2), 64) + 2;
      int wc = min(max(w0, -2), 64) + 2;
      float mh1 = m * ah, mh0 = m - mh1;
      float c01 = mh0 * aw, c00 = mh0 - c01;
      float c11 = mh1 * aw, c10 = mh1 - c11;
      recs[r]            = c00;
      recs[576 + r]      = c01;
      recs[1152 + r]     = c10;
      recs[1728 + r]     = c11;
      recs[2304 + r]     = __uint_as_float((unsigned)((hc * PDIM + wc) << 5));
    }
  }
  __syncthreads();

  const int px = t >> 6;
  const int g = (t >> 2) & 15;
  const int q = t & 3;
  const int p = pblk + px;
  const int xsel = q >> 1;
  const u16* lanebase = h1p + (size_t)(img * 16 + g) * PIMG * 16 + q * 8;
  const int ri = px * 144 + g * 9;
  const float* ctp = &recs[xsel * 576 + ri];
  const float* cbp = &recs[1152 + xsel * 576 + ri];
  const float* adp = &recs[2304 + ri];

  float acc[8] = {};
  #pragma unroll
  for (int k = 0; k < 9; ++k){
    float ct = ctp[k];
    float cb = cbp[k];
    unsigned off = __float_as_uint(adp[k]);
    const u16* c0 = (const u16*)((const char*)lanebase + off);
    u16x8 tv = *reinterpret_cast<const u16x8*>(c0);
    u16x8 bv = *reinterpret_cast<const u16x8*>(c0 + PDIM * 16);
    #pragma unroll
    for (int j = 0; j < 8; ++j)
      acc[j] += ct * b2f(tv[j]) + cb * b2f(bv[j]);
  }
  #pragma unroll
  for (int j = 0; j < 8; ++j)
    acc[j] += __shfl_xor(acc[j], 2, 64);
  if (q < 2){
    u16x8 o8;
    #pragma unroll
    for (int j = 0; j < 8; ++j) o8[j] = f2b(acc[j]);
    *reinterpret_cast<u16x8*>(&ydcn[(size_t)p * 256 + g * 16 + q * 8]) = o8;
  }
}

// ---------------------------------------------------------------------------
// k_gemm2: conv2 + BN + SiLU, tile 128x128, out fp32 NCHW (write-bound).
// ---------------------------------------------------------------------------
__global__ __launch_bounds__(256) void k_gemm2(const u16* __restrict__ A,
    const u16* __restrict__ Bw, const float* __restrict__ bnA,
    const float* __restrict__ bnB, float* __restrict__ out){
  __shared__ __align__(16) u16 smem[(128 + 128) * 40];
  const int t = threadIdx.x;
  const int tm = blockIdx.x * 128;
  const int tn = blockIdx.y * 128;
  const int lane = t & 63;
  const int wid = t >> 6;
  const int wr = wid >> 1, wc = wid & 1;
  constexpr int BOFF = 128 * 40;

  f32x4 acc[4][4] = {};

  for (int kc = 0; kc < 256; kc += 32){
    #pragma unroll
    for (int i = 0; i < 2; ++i){
      int v = t + i * 256;
      int row = v >> 2, cq = v & 3;
      *reinterpret_cast<u16x8*>(&smem[row * 40 + cq * 8]) =
        *reinterpret_cast<const u16x8*>(&A[(size_t)(tm + row) * 256 + kc + cq * 8]);
    }
    #pragma unroll
    for (int i = 0; i < 2; ++i){
      int v = t + i * 256;
      int row = v >> 2, cq = v & 3;
      *reinterpret_cast<u16x8*>(&smem[BOFF + row * 40 + cq * 8]) =
        *reinterpret_cast<const u16x8*>(&Bw[(size_t)(tn + row) * 256 + kc + cq * 8]);
    }
    __syncthreads();
    short8 af[4], bf[4];
    #pragma unroll
    for (int m = 0; m < 4; ++m)
      af[m] = *reinterpret_cast<const short8*>(
        &smem[(wr * 64 + m * 16 + (lane & 15)) * 40 + (lane >> 4) * 8]);
    #pragma unroll
    for (int n = 0; n < 4; ++n)
      bf[n] = *reinterpret_cast<const short8*>(
        &smem[BOFF + (wc * 64 + n * 16 + (lane & 15)) * 40 + (lane >> 4) * 8]);
    #pragma unroll
    for (int m = 0; m < 4; ++m)
      #pragma unroll
      for (int n = 0; n < 4; ++n)
        acc[m][n] = __builtin_amdgcn_mfma_f32_16x16x32_bf16(af[m], bf[n], acc[m][n], 0, 0, 0);
    __syncthreads();
  }

  const int bimg = tm >> 12;
  const int ploc = tm & 4095;
  #pragma unroll
  for (int n = 0; n < 4; ++n){
    int o = tn + wc * 64 + n * 16 + (lane & 15);
    float sA = bnA[o], sB = bnB[o];
    #pragma unroll
    for (int m = 0; m < 4; ++m){
      int prow = wr * 64 + m * 16 + ((lane >> 4) << 2);
      f32x4 st;
      #pragma unroll
      for (int j = 0; j < 4; ++j){
        float y = acc[m][n][j] * sA + sB;
        st[j] = y / (1.f + expf(-y));
      }
      *reinterpret_cast<f32x4*>(&out[((size_t)(bimg * 256 + o)) * HW + ploc + prow]) = st;
    }
  }
}

extern "C" void kernel_launch(void* const* d_in, const int* in_sizes, int n_in,
                              void* d_out, int out_size, void* d_ws, size_t ws_size,
                              hipStream_t stream) {
  const float* x     = (const float*)d_in[0];
  const float* w1    = (const float*)d_in[1];
  const float* b1    = (const float*)d_in[2];
  const float* woff  = (const float*)d_in[3];
  const float* boff  = (const float*)d_in[4];
  const float* w2    = (const float*)d_in[5];
  const float* gamma = (const float*)d_in[6];
  const float* beta  = (const float*)d_in[7];
  const float* mean  = (const float*)d_in[8];
  const float* var   = (const float*)d_in[9];
  float* out = (float*)d_out;
  (void)in_sizes; (void)n_in; (void)out_size; (void)ws_size;

  u16* h1p    = (u16*)d_ws;                               // 128 planes * 4624 * 32B = 18.9 MB
  u16* om     = h1p + (size_t)128 * PIMG * 16;            // 32768*432 = 28.3 MB
  u16* xT     = om + (size_t)PTOT * MOFF;                 // 32768*256 = 16.8 MB
  u16* ydcn   = xT + (size_t)PTOT * CCH;                  // 32768*256 = 16.8 MB
  u16* wb_big = ydcn + (size_t)PTOT * CCH;                // 768*256 bf16
  u16* wb2    = wb_big + 768 * 256;                       // 256*256
  float* bnA  = (float*)(wb2 + 256 * 256);
  float* bnB  = bnA + 256;
  float* bcomb = bnB + 256;                               // 432 f32

  dim3 blk(256);
  k_prep<<<dim3(3601), blk, 0, stream>>>(x, w1, w2, woff, b1, boff,
                                         gamma, beta, mean, var,
                                         xT, wb_big, wb2, bnA, bnB, bcomb, h1p);
  k_gemm_big<<<dim3(768), blk, 0, stream>>>(xT, wb_big, b1, bcomb, h1p, om);
  k_sample<<<dim3(PTOT / 4), blk, 0, stream>>>(h1p, om, ydcn);
  k_gemm2<<<dim3(PTOT / 128, 2), blk, 0, stream>>>(ydcn, wb2, bnA, bnB, out);
}